// Round 2
// 375.841 us; speedup vs baseline: 1.0939x; 1.0939x over previous
//
#include <hip/hip_runtime.h>
#include <hip/hip_bf16.h>

#define BM 128
#define BN 128
#define BK 32
#define TILE_ELEMS (BM * BK)   // 4096 u16 = 8 KB

typedef __attribute__((ext_vector_type(4))) float floatx4;
typedef __bf16 bf16x8 __attribute__((ext_vector_type(8)));
typedef unsigned int u32;
typedef unsigned short u16;

typedef __attribute__((address_space(1))) const u32 g_u32;
typedef __attribute__((address_space(3))) u32 l_u32;

__device__ __forceinline__ u16 f32_to_bf16(float f) {
    union { float f; u32 u; } x{f};
    u32 u = x.u;
    u32 r = (u + 0x7fffu + ((u >> 16) & 1u)) >> 16;
    return (u16)r;
}

// ============================================================================
// 8-phase 256x256 QKV GEMM (T1 xcd-swizzle + T2 lds-swizzle + T3/T4 counted
// vmcnt + T5 setprio). C[16384][3072] = X[16384][1024] . W[3072][1024]^T, bf16.
// 512 thr / 8 waves (2M x 4N), BK=64, 128 KiB dbuf LDS, 1 block/CU.
// ============================================================================

// Stage a 128x64 bf16 half-tile into LDS. LDS dest is LINEAR (required by
// global_load_lds); the T2 swizzle (16B slot ^= row&7) is applied by
// permuting the per-lane GLOBAL source column (rule #21: both-sides swizzle
// via pre-swizzled source + swizzled ds_read).
__device__ __forceinline__ void stage_half_sw(const u16* gbase, u16* lds_half, int tid) {
    int lane = tid & 63;
    int rsub = lane >> 3;                        // 0..7 row within 8-row slab
    int colsw = ((lane & 7) ^ rsub) << 3;        // swizzled source column (elems)
#pragma unroll
    for (int j = 0; j < 2; ++j) {
        int q = (tid >> 6) * 2 + j;              // 8-row slab index 0..15
        int row = q * 8 + rsub;
        const u16* g = gbase + row * 1024 + colsw;
        u16* l = lds_half + q * 512 + lane * 8;  // linear: wave base + lane*16B
        __builtin_amdgcn_global_load_lds((g_u32*)g, (l_u32*)l, 16, 0, 0);
    }
}

__global__ __launch_bounds__(512, 2)
void qkv_gemm8(const u16* __restrict__ A, const u16* __restrict__ Bw, u16* __restrict__ C)
{
    __shared__ u16 As[2][256 * 64];   // [buf][256 rows x 64 cols], 32 KiB each
    __shared__ u16 Bs[2][256 * 64];

    // T1: bijective XCD-chunked swizzle (768 % 8 == 0). mt-major within chunk:
    // 8 A-panels hot in L2 per XCD, all 12 W-panels L2/L3 resident.
    int bid = blockIdx.x;
    int wg = (bid & 7) * 96 + (bid >> 3);
    int mt = wg / 12, nt = wg - mt * 12;

    int tid = threadIdx.x;
    int lane = tid & 63, wv = tid >> 6;
    int wr = wv >> 2, wc = wv & 3;               // wave grid 2M x 4N
    int lrow = lane & 15, quad = lane >> 4;
    int sw = lrow & 7;                           // read-side swizzle XOR

    const u16* Ab = A + (long)mt * 256 * 1024;
    const u16* Bb = Bw + (long)nt * 256 * 1024;

    // Prologue: stage B(0), A(0), B(1)  (12 loads). Wait first 8, barrier.
    stage_half_sw(Bb,                  &Bs[0][0],        tid);
    stage_half_sw(Bb + 128 * 1024,     &Bs[0][128 * 64], tid);
    stage_half_sw(Ab,                  &As[0][0],        tid);
    stage_half_sw(Ab + 128 * 1024,     &As[0][128 * 64], tid);
    stage_half_sw(Bb + 64,             &Bs[1][0],        tid);
    stage_half_sw(Bb + 64 + 128 * 1024,&Bs[1][128 * 64], tid);
    asm volatile("s_waitcnt vmcnt(4)" ::: "memory");
    __builtin_amdgcn_sched_barrier(0);
    __builtin_amdgcn_s_barrier();

    floatx4 acc[8][4] = {};

    const int arow = (wr * 128 + lrow) * 64;     // elem offset of frag row
    const int brow = (wc * 64 + lrow) * 64;
    const int sl0 = (quad ^ sw) * 8;             // kk=0 swizzled 16B slot
    const int sl1 = ((4 + quad) ^ sw) * 8;       // kk=1

    // 16 K-tiles of 64, 2 per iteration. Stage slots per iteration i
    // (tile t0=2i in buf0 at P1-4, t1=2i+1 in buf1 at P5-8):
    //   P1,P2: A(t1)->As[1]   (prev tenant's reads ended last iter P8)
    //   P3,P4: B(t0+2)->Bs[0] (B(t0) fully read at P1)
    //   P5,P6: A(t0+2)->As[0] (A(t0) fully read at P4)
    //   P7,P8: B(t1+2)->Bs[1] (B(t1) fully read at P5)
    // vmcnt(4) before P4-end barrier (covers A(t1),B(t1) for P5) and before
    // P8-end barrier (covers A(t0+2),B(t0+2) for next P1). Never vmcnt(0).
    for (int i = 0; i < 8; ++i) {
        int t1  = 2 * i + 1;
        int tn  = (2 * i + 2 <= 15) ? 2 * i + 2 : 15;   // clamp: tail re-stages
        int tn1 = (2 * i + 3 <= 15) ? 2 * i + 3 : 15;   // valid data, never read
        const u16* gA1 = Ab + t1 * 64;
        const u16* gB2 = Bb + tn * 64;
        const u16* gA2 = Ab + tn * 64;
        const u16* gB3 = Bb + tn1 * 64;

        bf16x8 bq0[4], bq1[4];
#pragma unroll
        for (int half = 0; half < 2; ++half) {
#pragma unroll
            for (int p = 0; p < 4; ++p) {
                // ---- ds-reads for this phase (B once per tile at p==0) ----
                if (p == 0) {
#pragma unroll
                    for (int ni = 0; ni < 4; ++ni) {
                        bq0[ni] = *(const bf16x8*)&Bs[half][brow + ni * 1024 + sl0];
                        bq1[ni] = *(const bf16x8*)&Bs[half][brow + ni * 1024 + sl1];
                    }
                }
                bf16x8 a00 = *(const bf16x8*)&As[half][arow + (2 * p)     * 1024 + sl0];
                bf16x8 a01 = *(const bf16x8*)&As[half][arow + (2 * p)     * 1024 + sl1];
                bf16x8 a10 = *(const bf16x8*)&As[half][arow + (2 * p + 1) * 1024 + sl0];
                bf16x8 a11 = *(const bf16x8*)&As[half][arow + (2 * p + 1) * 1024 + sl1];

                // ---- stage one half-tile ----
                int ph = half * 4 + p;
                switch (ph) {
                    case 0: stage_half_sw(gA1,              &As[1][0],        tid); break;
                    case 1: stage_half_sw(gA1 + 128 * 1024, &As[1][128 * 64], tid); break;
                    case 2: stage_half_sw(gB2,              &Bs[0][0],        tid); break;
                    case 3: stage_half_sw(gB2 + 128 * 1024, &Bs[0][128 * 64], tid); break;
                    case 4: stage_half_sw(gA2,              &As[0][0],        tid); break;
                    case 5: stage_half_sw(gA2 + 128 * 1024, &As[0][128 * 64], tid); break;
                    case 6: stage_half_sw(gB3,              &Bs[1][0],        tid); break;
                    case 7: stage_half_sw(gB3 + 128 * 1024, &Bs[1][128 * 64], tid); break;
                }

                __builtin_amdgcn_s_barrier();
                __builtin_amdgcn_s_setprio(1);
                int m0 = 2 * p;
#pragma unroll
                for (int ni = 0; ni < 4; ++ni) {
                    acc[m0][ni]     = __builtin_amdgcn_mfma_f32_16x16x32_bf16(a00, bq0[ni], acc[m0][ni],     0, 0, 0);
                    acc[m0][ni]     = __builtin_amdgcn_mfma_f32_16x16x32_bf16(a01, bq1[ni], acc[m0][ni],     0, 0, 0);
                    acc[m0 + 1][ni] = __builtin_amdgcn_mfma_f32_16x16x32_bf16(a10, bq0[ni], acc[m0 + 1][ni], 0, 0, 0);
                    acc[m0 + 1][ni] = __builtin_amdgcn_mfma_f32_16x16x32_bf16(a11, bq1[ni], acc[m0 + 1][ni], 0, 0, 0);
                }
                __builtin_amdgcn_s_setprio(0);
                if (p == 3) {
                    asm volatile("s_waitcnt vmcnt(4)" ::: "memory");
                    __builtin_amdgcn_sched_barrier(0);
                }
                __builtin_amdgcn_s_barrier();
            }
        }
    }
    asm volatile("s_waitcnt vmcnt(0)" ::: "memory");  // drain tail stages
    __builtin_amdgcn_sched_barrier(0);

    // Epilogue: C/D layout col = lane&15, row = quad*4 + r
    long crow0 = (long)mt * 256 + wr * 128 + quad * 4;
    int  ccol0 = nt * 256 + wc * 64 + lrow;
#pragma unroll
    for (int mi = 0; mi < 8; ++mi) {
#pragma unroll
        for (int r = 0; r < 4; ++r) {
            long row = crow0 + mi * 16 + r;
#pragma unroll
            for (int ni = 0; ni < 4; ++ni) {
                int col = ccol0 + ni * 16;
                C[row * 3072 + col] = f32_to_bf16(acc[mi][ni][r]);
            }
        }
    }
}

// ============================================================================
// Verified m97-structure path for S and PV (unchanged this round).
// ============================================================================

// Stage a BM x BK (rows x cols) bf16 tile into LDS via global_load_lds width=16.
// LDS layout: row-major [128][32], contiguous (required by global_load_lds).
__device__ __forceinline__ void stage_tile(const u16* gbase, int ld, u16* lds, int tid) {
#pragma unroll
    for (int it = 0; it < 2; ++it) {
        int flat = it * 2048 + tid * 8;       // element index into 128*32 tile
        int row = flat >> 5;                  // /32
        int col = flat & 31;
        const u16* g = gbase + (long)row * ld + col;
        __builtin_amdgcn_global_load_lds((g_u32*)g, (l_u32*)(&lds[flat]), 16, 0, 0);
    }
}

// C[m0+.., n0+..] = scale * sum_k A[m,k] * B[n,k]  (A,B row-major, K-contiguous)
// m97-shape K-loop (dbuf measured slower in R4 — do not re-add).
// MODE 0: plain store (bf16 if OUT_BF16 else fp32)
// MODE 1: score epilogue — store exp(scale*acc) bf16, causal-mask (col>row -> 0),
//         accumulate per-row sums into lsum via 16-lane shuffle + atomicAdd.
// MODE 2: PV epilogue — store fp32 acc * (1/lsum[row]).
template<bool OUT_BF16, int MODE>
__device__ __forceinline__ void gemm_body(
    const u16* __restrict__ Ab, const u16* __restrict__ Bb, void* __restrict__ Cb,
    int lda, int ldb, long ldc, int m0, int n0, int nkt, float scale,
    u16* As, u16* Bs, float* lsum)
{
    int tid = threadIdx.x;

    const u16* Arow = Ab + (long)m0 * lda;
    const u16* Brow = Bb + (long)n0 * ldb;

    stage_tile(Arow, lda, As, tid);
    stage_tile(Brow, ldb, Bs, tid);

    int wave = tid >> 6, lane = tid & 63;
    int wr = (wave >> 1) * 64, wc = (wave & 1) * 64;
    int lrow = lane & 15, quad = lane >> 4;

    floatx4 acc[4][4] = {};
    const int aoff = (wr + lrow) * BK + quad * 8;
    const int boff = (wc + lrow) * BK + quad * 8;

    for (int kt = 0; kt < nkt; ++kt) {
        __syncthreads();   // drains vmcnt: staged tile is in LDS
        bf16x8 af[4], bfr[4];
#pragma unroll
        for (int i = 0; i < 4; ++i) {
            af[i]  = *(const bf16x8*)&As[aoff + i * 16 * BK];
            bfr[i] = *(const bf16x8*)&Bs[boff + i * 16 * BK];
        }
#pragma unroll
        for (int mi = 0; mi < 4; ++mi)
#pragma unroll
            for (int ni = 0; ni < 4; ++ni)
                acc[mi][ni] = __builtin_amdgcn_mfma_f32_16x16x32_bf16(af[mi], bfr[ni], acc[mi][ni], 0, 0, 0);
        __syncthreads();   // all reads done before restage
        if (kt + 1 < nkt) {
            stage_tile(Arow + (kt + 1) * BK, lda, As, tid);
            stage_tile(Brow + (kt + 1) * BK, ldb, Bs, tid);
        }
    }

    // Epilogue: C/D layout col = lane&15, row = quad*4 + r
    long crow0 = m0 + wr + quad * 4;
    int  ccol0 = n0 + wc + lrow;
#pragma unroll
    for (int mi = 0; mi < 4; ++mi) {
#pragma unroll
        for (int r = 0; r < 4; ++r) {
            long row = crow0 + mi * 16 + r;
            float rs = 0.f;
            float linv = 1.f;
            if (MODE == 2) linv = 1.0f / lsum[row];
#pragma unroll
            for (int ni = 0; ni < 4; ++ni) {
                long col = ccol0 + ni * 16;
                float v = acc[mi][ni][r] * scale;
                if (MODE == 1) {
                    // causal: strictly-upper entries (only occur in diagonal
                    // tiles) -> 0. No max-shift: |score| <~ 8, exp safe in fp32.
                    float e = (col > row) ? 0.f : __expf(v);
                    ((u16*)Cb)[row * ldc + col] = f32_to_bf16(e);
                    rs += e;
                } else if (MODE == 2) {
                    ((float*)Cb)[row * ldc + col] = v * linv;
                } else {
                    if (OUT_BF16) ((u16*)Cb)[row * ldc + col] = f32_to_bf16(v);
                    else          ((float*)Cb)[row * ldc + col] = v;
                }
            }
            if (MODE == 1) {
                // reduce over the 16 lanes of this quad-group (cols wc..wc+63)
                rs += __shfl_xor(rs, 1, 16);
                rs += __shfl_xor(rs, 2, 16);
                rs += __shfl_xor(rs, 4, 16);
                rs += __shfl_xor(rs, 8, 16);
                if (lrow == 0) atomicAdd(&lsum[row], rs);
            }
        }
    }
}

// Ptilde = exp(Q.K^T / 32) with causal mask, lower-tri tiles only (17x8 fold).
// Row sums accumulate into lsum[b*2048 + row]. blockIdx.x = batch -> XCD.
__global__ __launch_bounds__(256)
void s_gemm(const u16* __restrict__ QKVi, u16* __restrict__ P, float* __restrict__ lsum)
{
    __shared__ u16 As[TILE_ELEMS];
    __shared__ u16 Bs[TILE_ELEMS];
    int b = blockIdx.x, u = blockIdx.y, v = blockIdx.z;
    int mt, nt;
    if (u <= v) { mt = v; nt = u; } else { mt = 15 - v; nt = u - v - 1; }
    const u16* Ab = QKVi + (long)b * 2048 * 3072;        // Q at col 0
    const u16* Bb = Ab + 1024;                            // K at col 1024
    gemm_body<true, 1>(Ab, Bb, P + (long)b * 2048 * 2048, 3072, 3072, 2048,
                       mt * BM, nt * BN, 32, 0.03125f, As, Bs, lsum + b * 2048);
}

// O = (Ptilde.V) / lsum, causal K-limit (Keff = m0+128). blockIdx.x = batch.
__global__ __launch_bounds__(256)
void pv_gemm(const u16* __restrict__ P, const u16* __restrict__ Vt,
             float* __restrict__ O, const float* __restrict__ lsum)
{
    __shared__ u16 As[TILE_ELEMS];
    __shared__ u16 Bs[TILE_ELEMS];
    int b = blockIdx.x, nt = blockIdx.y, mt = blockIdx.z;
    const u16* Ab = P + (long)b * 2048 * 2048;
    const u16* Bb = Vt + (long)b * 2048;                  // ldb = 16384 (all tokens)
    gemm_body<false, 2>(Ab, Bb, O + (long)b * 2048 * 1024, 2048, 16384, 1024,
                        mt * BM, nt * BN, mt * 4 + 4, 1.0f, As, Bs,
                        (float*)lsum + b * 2048);
}

__global__ __launch_bounds__(256)
void cvt_f32_bf16(const float* __restrict__ src, u16* __restrict__ dst, long n)
{
    long idx = ((long)blockIdx.x * 256 + threadIdx.x) << 2;
    if (idx >= n) return;
    float4 f = *(const float4*)(src + idx);
    ushort4 o;
    o.x = f32_to_bf16(f.x); o.y = f32_to_bf16(f.y);
    o.z = f32_to_bf16(f.z); o.w = f32_to_bf16(f.w);
    *(ushort4*)(dst + idx) = o;
}

// Convert all three weight matrices in one launch (1024 blocks/matrix).
__global__ __launch_bounds__(256)
void cvt_w3(const float* __restrict__ Wq, const float* __restrict__ Wk,
            const float* __restrict__ Wv, u16* __restrict__ dst)
{
    int which = blockIdx.x >> 10;
    const float* src = which == 0 ? Wq : (which == 1 ? Wk : Wv);
    long base = (long)(blockIdx.x & 1023) * 1024 + threadIdx.x * 4;
    float4 f = *(const float4*)(src + base);
    ushort4 o;
    o.x = f32_to_bf16(f.x); o.y = f32_to_bf16(f.y);
    o.z = f32_to_bf16(f.z); o.w = f32_to_bf16(f.w);
    *(ushort4*)(dst + (long)which * 1048576 + base) = o;
}

// Transpose V slice of QKVi (cols 2048..3071) -> Vt[1024][16384], 64x64 LDS tiles.
__global__ __launch_bounds__(256)
void transpose_v(const u16* __restrict__ QKVi, u16* __restrict__ Vt)
{
    __shared__ u16 tile[64][64 + 8];
    int t0 = blockIdx.x * 64;            // token tile (256)
    int d0 = blockIdx.y * 64;            // dv tile (16)
    int tid = threadIdx.x;
    int lr = tid >> 3, lc = (tid & 7) * 8;
#pragma unroll
    for (int p = 0; p < 2; ++p) {
        int tok = lr + p * 32;
        const u16* src = QKVi + (long)(t0 + tok) * 3072 + 2048 + d0 + lc;
        *(uint4*)&tile[tok][lc] = *(const uint4*)src;
    }
    __syncthreads();
#pragma unroll
    for (int p = 0; p < 2; ++p) {
        int dq = lr + p * 32;
        u16 vals[8];
#pragma unroll
        for (int i = 0; i < 8; ++i) vals[i] = tile[lc + i][dq];
        *(uint4*)(Vt + (long)(d0 + dq) * 16384 + t0 + lc) = *(const uint4*)vals;
    }
}

extern "C" void kernel_launch(void* const* d_in, const int* in_sizes, int n_in,
                              void* d_out, int out_size, void* d_ws, size_t ws_size,
                              hipStream_t stream)
{
    const int B = 8, N = 2048, D = 1024;
    const long MT = (long)B * N;          // 16384
    const long nX = MT * D;               // 16,777,216
    const long nW = (long)D * D;          // 1,048,576

    const float* x  = (const float*)d_in[0];
    const float* Wq = (const float*)d_in[1];
    const float* Wk = (const float*)d_in[2];
    const float* Wv = (const float*)d_in[3];
    float* out = (float*)d_out;

    // ws layout:
    u16* wb   = (u16*)d_ws;        // [3072][1024] stacked Wq;Wk;Wv; dead after qkv
    u16* xb   = wb + 3 * nW;       // [16384][1024]; reused as Vt after QKV gemm
    u16* QKVi = xb + nX;           // [16384][3072] interleaved Q|K|V
    u16* P    = QKVi + 3 * nX;     // [8][2048][2048] exp(scores), unnormalized
    u16* Vt   = xb;                // alias: [1024][16384]
    float* lsum = (float*)wb;      // alias: [8][2048] row sums (wb dead after qkv)

    // 1) fp32 -> bf16
    cvt_f32_bf16<<<(int)(nX / 1024), 256, 0, stream>>>(x, xb, nX);
    cvt_w3<<<3072, 256, 0, stream>>>(Wq, Wk, Wv, wb);

    // 2) fused QKV projection — 256^2 8-phase pipeline
    qkv_gemm8<<<dim3(768, 1, 1), 512, 0, stream>>>(xb, wb, QKVi);

    // 3) zero row-sum accumulator (wb now dead); V -> Vt (xb now dead)
    hipMemsetAsync(lsum, 0, (size_t)B * N * sizeof(float), stream);
    transpose_v<<<dim3(256, 16, 1), 256, 0, stream>>>(QKVi, Vt);

    // 4) Ptilde = exp(Q.K^T/32) masked, + row sums. Triangular tiles only.
    s_gemm<<<dim3(8, 17, 8), 256, 0, stream>>>(QKVi, P, lsum);

    // 5) O = Ptilde.V / lsum, K-limited
    pv_gemm<<<dim3(8, 8, 16), 256, 0, stream>>>(P, Vt, out, lsum);
}

// Round 3
// 361.053 us; speedup vs baseline: 1.1387x; 1.0410x over previous
//
#include <hip/hip_runtime.h>
#include <hip/hip_bf16.h>

#define BM 128
#define BN 128
#define BK 32
#define TILE_ELEMS (BM * BK)   // 4096 u16 = 8 KB

typedef __attribute__((ext_vector_type(4))) float floatx4;
typedef __bf16 bf16x8 __attribute__((ext_vector_type(8)));
typedef unsigned int u32;
typedef unsigned short u16;

typedef __attribute__((address_space(1))) const u32 g_u32;
typedef __attribute__((address_space(3))) u32 l_u32;

__device__ __forceinline__ u16 f32_to_bf16(float f) {
    union { float f; u32 u; } x{f};
    u32 u = x.u;
    u32 r = (u + 0x7fffu + ((u >> 16) & 1u)) >> 16;
    return (u16)r;
}

// ============================================================================
// 8-phase 256x256 QKV GEMM (T1+T2+T3/T4+T5). Verified R2: 112 µs, 0 bank
// conflicts, MfmaUtil 38.7%. Core schedule UNCHANGED this round; epilogue now
// writes Q,K to QKi[16384][2048] and V TRANSPOSED to Vt[1024][16384] (fuses
// the old transpose_v kernel; saves 67 MB of traffic + a launch).
// ============================================================================

__device__ __forceinline__ void stage_half_sw(const u16* gbase, u16* lds_half, int tid) {
    int lane = tid & 63;
    int rsub = lane >> 3;                        // 0..7 row within 8-row slab
    int colsw = ((lane & 7) ^ rsub) << 3;        // swizzled source column (elems)
#pragma unroll
    for (int j = 0; j < 2; ++j) {
        int q = (tid >> 6) * 2 + j;              // 8-row slab index 0..15
        int row = q * 8 + rsub;
        const u16* g = gbase + row * 1024 + colsw;
        u16* l = lds_half + q * 512 + lane * 8;  // linear: wave base + lane*16B
        __builtin_amdgcn_global_load_lds((g_u32*)g, (l_u32*)l, 16, 0, 0);
    }
}

__global__ __launch_bounds__(512, 2)
void qkv_gemm8(const u16* __restrict__ A, const u16* __restrict__ Bw,
               u16* __restrict__ QKi, u16* __restrict__ Vt)
{
    __shared__ u16 As[2][256 * 64];   // [buf][256 rows x 64 cols], 32 KiB each
    __shared__ u16 Bs[2][256 * 64];

    // T1: bijective XCD-chunked swizzle (768 % 8 == 0), mt-major within chunk.
    int bid = blockIdx.x;
    int wg = (bid & 7) * 96 + (bid >> 3);
    int mt = wg / 12, nt = wg - mt * 12;

    int tid = threadIdx.x;
    int lane = tid & 63, wv = tid >> 6;
    int wr = wv >> 2, wc = wv & 3;               // wave grid 2M x 4N
    int lrow = lane & 15, quad = lane >> 4;
    int sw = lrow & 7;                           // read-side swizzle XOR

    const u16* Ab = A + (long)mt * 256 * 1024;
    const u16* Bb = Bw + (long)nt * 256 * 1024;

    // Prologue: stage B(0), A(0), B(1)  (12 loads). Wait first 8, barrier.
    stage_half_sw(Bb,                  &Bs[0][0],        tid);
    stage_half_sw(Bb + 128 * 1024,     &Bs[0][128 * 64], tid);
    stage_half_sw(Ab,                  &As[0][0],        tid);
    stage_half_sw(Ab + 128 * 1024,     &As[0][128 * 64], tid);
    stage_half_sw(Bb + 64,             &Bs[1][0],        tid);
    stage_half_sw(Bb + 64 + 128 * 1024,&Bs[1][128 * 64], tid);
    asm volatile("s_waitcnt vmcnt(4)" ::: "memory");
    __builtin_amdgcn_sched_barrier(0);
    __builtin_amdgcn_s_barrier();

    floatx4 acc[8][4] = {};

    const int arow = (wr * 128 + lrow) * 64;     // elem offset of frag row
    const int brow = (wc * 64 + lrow) * 64;
    const int sl0 = (quad ^ sw) * 8;             // kk=0 swizzled 16B slot
    const int sl1 = ((4 + quad) ^ sw) * 8;       // kk=1

    for (int i = 0; i < 8; ++i) {
        int t1  = 2 * i + 1;
        int tn  = (2 * i + 2 <= 15) ? 2 * i + 2 : 15;   // clamp: tail re-stages
        int tn1 = (2 * i + 3 <= 15) ? 2 * i + 3 : 15;   // valid data, never read
        const u16* gA1 = Ab + t1 * 64;
        const u16* gB2 = Bb + tn * 64;
        const u16* gA2 = Ab + tn * 64;
        const u16* gB3 = Bb + tn1 * 64;

        bf16x8 bq0[4], bq1[4];
#pragma unroll
        for (int half = 0; half < 2; ++half) {
#pragma unroll
            for (int p = 0; p < 4; ++p) {
                if (p == 0) {
#pragma unroll
                    for (int ni = 0; ni < 4; ++ni) {
                        bq0[ni] = *(const bf16x8*)&Bs[half][brow + ni * 1024 + sl0];
                        bq1[ni] = *(const bf16x8*)&Bs[half][brow + ni * 1024 + sl1];
                    }
                }
                bf16x8 a00 = *(const bf16x8*)&As[half][arow + (2 * p)     * 1024 + sl0];
                bf16x8 a01 = *(const bf16x8*)&As[half][arow + (2 * p)     * 1024 + sl1];
                bf16x8 a10 = *(const bf16x8*)&As[half][arow + (2 * p + 1) * 1024 + sl0];
                bf16x8 a11 = *(const bf16x8*)&As[half][arow + (2 * p + 1) * 1024 + sl1];

                int ph = half * 4 + p;
                switch (ph) {
                    case 0: stage_half_sw(gA1,              &As[1][0],        tid); break;
                    case 1: stage_half_sw(gA1 + 128 * 1024, &As[1][128 * 64], tid); break;
                    case 2: stage_half_sw(gB2,              &Bs[0][0],        tid); break;
                    case 3: stage_half_sw(gB2 + 128 * 1024, &Bs[0][128 * 64], tid); break;
                    case 4: stage_half_sw(gA2,              &As[0][0],        tid); break;
                    case 5: stage_half_sw(gA2 + 128 * 1024, &As[0][128 * 64], tid); break;
                    case 6: stage_half_sw(gB3,              &Bs[1][0],        tid); break;
                    case 7: stage_half_sw(gB3 + 128 * 1024, &Bs[1][128 * 64], tid); break;
                }

                __builtin_amdgcn_s_barrier();
                __builtin_amdgcn_s_setprio(1);
                int m0 = 2 * p;
#pragma unroll
                for (int ni = 0; ni < 4; ++ni) {
                    acc[m0][ni]     = __builtin_amdgcn_mfma_f32_16x16x32_bf16(a00, bq0[ni], acc[m0][ni],     0, 0, 0);
                    acc[m0][ni]     = __builtin_amdgcn_mfma_f32_16x16x32_bf16(a01, bq1[ni], acc[m0][ni],     0, 0, 0);
                    acc[m0 + 1][ni] = __builtin_amdgcn_mfma_f32_16x16x32_bf16(a10, bq0[ni], acc[m0 + 1][ni], 0, 0, 0);
                    acc[m0 + 1][ni] = __builtin_amdgcn_mfma_f32_16x16x32_bf16(a11, bq1[ni], acc[m0 + 1][ni], 0, 0, 0);
                }
                __builtin_amdgcn_s_setprio(0);
                if (p == 3) {
                    asm volatile("s_waitcnt vmcnt(4)" ::: "memory");
                    __builtin_amdgcn_sched_barrier(0);
                }
                __builtin_amdgcn_s_barrier();
            }
        }
    }
    asm volatile("s_waitcnt vmcnt(0)" ::: "memory");  // drain tail stages
    __builtin_amdgcn_sched_barrier(0);

    // Epilogue. C/D layout col = lane&15, row = quad*4 + r.
    if (nt < 8) {
        // Q,K part -> QKi [16384][2048]
        long crow0 = (long)mt * 256 + wr * 128 + quad * 4;
        int  ccol0 = nt * 256 + wc * 64 + lrow;
#pragma unroll
        for (int mi = 0; mi < 8; ++mi) {
#pragma unroll
            for (int r = 0; r < 4; ++r) {
                long row = crow0 + mi * 16 + r;
#pragma unroll
                for (int ni = 0; ni < 4; ++ni)
                    QKi[row * 2048 + ccol0 + ni * 16] = f32_to_bf16(acc[mi][ni][r]);
            }
        }
    } else {
        // V part -> Vt [1024][16384] transposed. Consecutive r = consecutive
        // tokens = contiguous in Vt row -> 8B packed stores.
        int dv0   = (nt - 8) * 256 + wc * 64 + lrow;
        long tok0 = (long)mt * 256 + wr * 128 + quad * 4;
#pragma unroll
        for (int mi = 0; mi < 8; ++mi) {
#pragma unroll
            for (int ni = 0; ni < 4; ++ni) {
                ushort4 o;
                o.x = f32_to_bf16(acc[mi][ni][0]);
                o.y = f32_to_bf16(acc[mi][ni][1]);
                o.z = f32_to_bf16(acc[mi][ni][2]);
                o.w = f32_to_bf16(acc[mi][ni][3]);
                *(ushort4*)(Vt + (long)(dv0 + ni * 16) * 16384 + tok0 + mi * 16) = o;
            }
        }
    }
}

// ============================================================================
// m97-structure S kernel (unchanged structure; strides now 2048 for QKi).
// ============================================================================

__device__ __forceinline__ void stage_tile(const u16* gbase, int ld, u16* lds, int tid) {
#pragma unroll
    for (int it = 0; it < 2; ++it) {
        int flat = it * 2048 + tid * 8;       // element index into 128*32 tile
        int row = flat >> 5;                  // /32
        int col = flat & 31;
        const u16* g = gbase + (long)row * ld + col;
        __builtin_amdgcn_global_load_lds((g_u32*)g, (l_u32*)(&lds[flat]), 16, 0, 0);
    }
}

// MODE 1: score epilogue — store exp(scale*acc) bf16, causal-mask, rowsum.
template<bool OUT_BF16, int MODE>
__device__ __forceinline__ void gemm_body(
    const u16* __restrict__ Ab, const u16* __restrict__ Bb, void* __restrict__ Cb,
    int lda, int ldb, long ldc, int m0, int n0, int nkt, float scale,
    u16* As, u16* Bs, float* lsum)
{
    int tid = threadIdx.x;

    const u16* Arow = Ab + (long)m0 * lda;
    const u16* Brow = Bb + (long)n0 * ldb;

    stage_tile(Arow, lda, As, tid);
    stage_tile(Brow, ldb, Bs, tid);

    int wave = tid >> 6, lane = tid & 63;
    int wr = (wave >> 1) * 64, wc = (wave & 1) * 64;
    int lrow = lane & 15, quad = lane >> 4;

    floatx4 acc[4][4] = {};
    const int aoff = (wr + lrow) * BK + quad * 8;
    const int boff = (wc + lrow) * BK + quad * 8;

    for (int kt = 0; kt < nkt; ++kt) {
        __syncthreads();   // drains vmcnt: staged tile is in LDS
        bf16x8 af[4], bfr[4];
#pragma unroll
        for (int i = 0; i < 4; ++i) {
            af[i]  = *(const bf16x8*)&As[aoff + i * 16 * BK];
            bfr[i] = *(const bf16x8*)&Bs[boff + i * 16 * BK];
        }
#pragma unroll
        for (int mi = 0; mi < 4; ++mi)
#pragma unroll
            for (int ni = 0; ni < 4; ++ni)
                acc[mi][ni] = __builtin_amdgcn_mfma_f32_16x16x32_bf16(af[mi], bfr[ni], acc[mi][ni], 0, 0, 0);
        __syncthreads();   // all reads done before restage
        if (kt + 1 < nkt) {
            stage_tile(Arow + (kt + 1) * BK, lda, As, tid);
            stage_tile(Brow + (kt + 1) * BK, ldb, Bs, tid);
        }
    }

    long crow0 = m0 + wr + quad * 4;
    int  ccol0 = n0 + wc + lrow;
#pragma unroll
    for (int mi = 0; mi < 4; ++mi) {
#pragma unroll
        for (int r = 0; r < 4; ++r) {
            long row = crow0 + mi * 16 + r;
            float rs = 0.f;
#pragma unroll
            for (int ni = 0; ni < 4; ++ni) {
                long col = ccol0 + ni * 16;
                float v = acc[mi][ni][r] * scale;
                if (MODE == 1) {
                    float e = (col > row) ? 0.f : __expf(v);
                    ((u16*)Cb)[row * ldc + col] = f32_to_bf16(e);
                    rs += e;
                } else {
                    if (OUT_BF16) ((u16*)Cb)[row * ldc + col] = f32_to_bf16(v);
                    else          ((float*)Cb)[row * ldc + col] = v;
                }
            }
            if (MODE == 1) {
                rs += __shfl_xor(rs, 1, 16);
                rs += __shfl_xor(rs, 2, 16);
                rs += __shfl_xor(rs, 4, 16);
                rs += __shfl_xor(rs, 8, 16);
                if (lrow == 0) atomicAdd(&lsum[row], rs);
            }
        }
    }
}

// Ptilde = exp(Q.K^T / 32) with causal mask, lower-tri tiles only (17x8 fold).
__global__ __launch_bounds__(256)
void s_gemm(const u16* __restrict__ QKi, u16* __restrict__ P, float* __restrict__ lsum)
{
    __shared__ u16 As[TILE_ELEMS];
    __shared__ u16 Bs[TILE_ELEMS];
    int b = blockIdx.x, u = blockIdx.y, v = blockIdx.z;
    int mt, nt;
    if (u <= v) { mt = v; nt = u; } else { mt = 15 - v; nt = u - v - 1; }
    const u16* Ab = QKi + (long)b * 2048 * 2048;          // Q at col 0
    const u16* Bb = Ab + 1024;                            // K at col 1024
    gemm_body<true, 1>(Ab, Bb, P + (long)b * 2048 * 2048, 2048, 2048, 2048,
                       mt * BM, nt * BN, 32, 0.03125f, As, Bs, lsum + b * 2048);
}

// ============================================================================
// PV: 128x256 tiles, 512 thr / 8 waves of 64x64. Halves P and Vt re-reads
// vs the 128x128 version (P read 4x not 8x; Vt likewise). m97 2-barrier loop.
// LPT: mt reversed so K=2048 tiles dispatch first.
// ============================================================================
__global__ __launch_bounds__(512)
void pv_gemm2(const u16* __restrict__ P, const u16* __restrict__ Vt,
              float* __restrict__ O, const float* __restrict__ lsum)
{
    __shared__ u16 As[128 * 32];   // 8 KB
    __shared__ u16 Bs[256 * 32];   // 16 KB
    int b = blockIdx.x, nt = blockIdx.y, mt = 15 - blockIdx.z;
    const u16* Ab = P  + (long)b * 2048 * 2048 + (long)mt * 128 * 2048;  // lda 2048
    const u16* Bb = Vt + (long)b * 2048 + (long)nt * 256 * 16384;        // ldb 16384
    float* Ob = O + (long)b * 2048 * 1024;
    const float* ls = lsum + b * 2048;
    int nkt = mt * 4 + 4;                         // Keff = (mt+1)*128

    int tid = threadIdx.x, lane = tid & 63, wave = tid >> 6;
    int wr = wave >> 2, wc = wave & 3;            // 2M x 4N waves of 64x64
    int lrow = lane & 15, quad = lane >> 4;

    // stage A (128x32 = 4096 elems = 512 thr * 8): one call
    // stage B (256x32 = 8192 elems): two calls
    {
        int flat = tid * 8, row = flat >> 5, col = flat & 31;
        __builtin_amdgcn_global_load_lds((g_u32*)(Ab + (long)row * 2048 + col),
                                         (l_u32*)&As[flat], 16, 0, 0);
#pragma unroll
        for (int it = 0; it < 2; ++it) {
            int f2 = it * 4096 + tid * 8, r2 = f2 >> 5, c2 = f2 & 31;
            __builtin_amdgcn_global_load_lds((g_u32*)(Bb + (long)r2 * 16384 + c2),
                                             (l_u32*)&Bs[f2], 16, 0, 0);
        }
    }

    floatx4 acc[4][4] = {};
    const int aoff = (wr * 64 + lrow) * 32 + quad * 8;
    const int boff = (wc * 64 + lrow) * 32 + quad * 8;

    for (int kt = 0; kt < nkt; ++kt) {
        __syncthreads();
        bf16x8 af[4], bfr[4];
#pragma unroll
        for (int i = 0; i < 4; ++i) {
            af[i]  = *(const bf16x8*)&As[aoff + i * 16 * 32];
            bfr[i] = *(const bf16x8*)&Bs[boff + i * 16 * 32];
        }
#pragma unroll
        for (int mi = 0; mi < 4; ++mi)
#pragma unroll
            for (int ni = 0; ni < 4; ++ni)
                acc[mi][ni] = __builtin_amdgcn_mfma_f32_16x16x32_bf16(af[mi], bfr[ni], acc[mi][ni], 0, 0, 0);
        __syncthreads();
        if (kt + 1 < nkt) {
            const u16* An = Ab + (kt + 1) * 32;
            const u16* Bn = Bb + (kt + 1) * 32;
            int flat = tid * 8, row = flat >> 5, col = flat & 31;
            __builtin_amdgcn_global_load_lds((g_u32*)(An + (long)row * 2048 + col),
                                             (l_u32*)&As[flat], 16, 0, 0);
#pragma unroll
            for (int it = 0; it < 2; ++it) {
                int f2 = it * 4096 + tid * 8, r2 = f2 >> 5, c2 = f2 & 31;
                __builtin_amdgcn_global_load_lds((g_u32*)(Bn + (long)r2 * 16384 + c2),
                                                 (l_u32*)&Bs[f2], 16, 0, 0);
            }
        }
    }

    // Epilogue: out = acc / lsum[row], fp32.
    int crow0 = mt * 128 + wr * 64 + quad * 4;
    int ccol0 = nt * 256 + wc * 64 + lrow;
#pragma unroll
    for (int mi = 0; mi < 4; ++mi) {
#pragma unroll
        for (int r = 0; r < 4; ++r) {
            int row = crow0 + mi * 16 + r;
            float linv = 1.0f / ls[row];
#pragma unroll
            for (int ni = 0; ni < 4; ++ni)
                Ob[(long)row * 1024 + ccol0 + ni * 16] = acc[mi][ni][r] * linv;
        }
    }
}

__global__ __launch_bounds__(256)
void cvt_f32_bf16(const float* __restrict__ src, u16* __restrict__ dst, long n)
{
    long idx = ((long)blockIdx.x * 256 + threadIdx.x) << 2;
    if (idx >= n) return;
    float4 f = *(const float4*)(src + idx);
    ushort4 o;
    o.x = f32_to_bf16(f.x); o.y = f32_to_bf16(f.y);
    o.z = f32_to_bf16(f.z); o.w = f32_to_bf16(f.w);
    *(ushort4*)(dst + idx) = o;
}

__global__ __launch_bounds__(256)
void cvt_w3(const float* __restrict__ Wq, const float* __restrict__ Wk,
            const float* __restrict__ Wv, u16* __restrict__ dst)
{
    int which = blockIdx.x >> 10;
    const float* src = which == 0 ? Wq : (which == 1 ? Wk : Wv);
    long base = (long)(blockIdx.x & 1023) * 1024 + threadIdx.x * 4;
    float4 f = *(const float4*)(src + base);
    ushort4 o;
    o.x = f32_to_bf16(f.x); o.y = f32_to_bf16(f.y);
    o.z = f32_to_bf16(f.z); o.w = f32_to_bf16(f.w);
    *(ushort4*)(dst + (long)which * 1048576 + base) = o;
}

extern "C" void kernel_launch(void* const* d_in, const int* in_sizes, int n_in,
                              void* d_out, int out_size, void* d_ws, size_t ws_size,
                              hipStream_t stream)
{
    const int B = 8, N = 2048, D = 1024;
    const long MT = (long)B * N;          // 16384
    const long nX = MT * D;               // 16,777,216
    const long nW = (long)D * D;          // 1,048,576

    const float* x  = (const float*)d_in[0];
    const float* Wq = (const float*)d_in[1];
    const float* Wk = (const float*)d_in[2];
    const float* Wv = (const float*)d_in[3];
    float* out = (float*)d_out;

    // ws layout (u16 units):
    u16* wb   = (u16*)d_ws;        // [3072][1024] stacked Wq;Wk;Wv; dead after qkv
    u16* xb   = wb + 3 * nW;       // [16384][1024] bf16 x
    u16* QKi  = xb + nX;           // [16384][2048] Q|K interleaved
    u16* Vt   = QKi + MT * 2048;   // [1024][16384] V transposed (written by qkv)
    u16* P    = Vt + nX;           // [8][2048][2048] exp(scores), unnormalized
    float* lsum = (float*)wb;      // alias: [8][2048] row sums (wb dead after qkv)

    // 1) fp32 -> bf16
    cvt_f32_bf16<<<(int)(nX / 1024), 256, 0, stream>>>(x, xb, nX);
    cvt_w3<<<3072, 256, 0, stream>>>(Wq, Wk, Wv, wb);

    // 2) fused QKV projection — 256^2 8-phase pipeline; V written transposed
    qkv_gemm8<<<dim3(768, 1, 1), 512, 0, stream>>>(xb, wb, QKi, Vt);

    // 3) zero row-sum accumulator (wb now dead)
    hipMemsetAsync(lsum, 0, (size_t)B * N * sizeof(float), stream);

    // 4) Ptilde = exp(Q.K^T/32) masked, + row sums. Triangular tiles only.
    s_gemm<<<dim3(8, 17, 8), 256, 0, stream>>>(QKi, P, lsum);

    // 5) O = Ptilde.V / lsum, K-limited. 128x256 tiles, LPT order.
    pv_gemm2<<<dim3(8, 4, 16), 512, 0, stream>>>(P, Vt, out, lsum);
}